// Round 6
// baseline (449.601 us; speedup 1.0000x reference)
//
#include <hip/hip_runtime.h>
#include <hip/hip_bf16.h>

typedef __bf16 bf16x8 __attribute__((ext_vector_type(8)));
typedef float  f32x4  __attribute__((ext_vector_type(4)));
typedef unsigned short us8 __attribute__((ext_vector_type(8)));

__device__ inline unsigned short f2bf(float f) {
    unsigned u = __builtin_bit_cast(unsigned, f);
    u += 0x7fffu + ((u >> 16) & 1u);
    return (unsigned short)(u >> 16);
}

__device__ inline bf16x8 load_frag(const unsigned short* p) {
    return *reinterpret_cast<const bf16x8*>(p);
}

// async global->LDS, 16 bytes per lane (wave-uniform LDS base + lane*16)
__device__ inline void gload_lds16(const unsigned short* g, unsigned short* l) {
    __builtin_amdgcn_global_load_lds(
        (const __attribute__((address_space(1))) void*)g,
        (__attribute__((address_space(3))) void*)l, 16, 0, 0);
}

// barrier that waits LDS ops only — leaves global_load_lds (vmcnt) in flight
__device__ inline void barrier_lds_only() {
    asm volatile("s_waitcnt lgkmcnt(0)\ns_barrier" ::: "memory");
}

// ---------------- fused prep: 6 weight transposes + qkv bias concat ----------------
__global__ void prep_kernel(const float* __restrict__ wq, const float* __restrict__ wk,
                            const float* __restrict__ wv, const float* __restrict__ wo,
                            const float* __restrict__ w1, const float* __restrict__ w2,
                            const float* __restrict__ bq, const float* __restrict__ bk,
                            const float* __restrict__ bv,
                            unsigned short* __restrict__ wqkvT, unsigned short* __restrict__ woT,
                            unsigned short* __restrict__ w1T, unsigned short* __restrict__ w2T,
                            float* __restrict__ biasqkv) {
    int bid = blockIdx.x;
    int tx = threadIdx.x, ty = threadIdx.y;  // (32, 8)
    if (bid >= 3072) {
        int i = (bid - 3072) * 256 + ty * 32 + tx;  // 0..1535
        float v = (i < 512) ? bq[i] : ((i < 1024) ? bk[i - 512] : bv[i - 1024]);
        biasqkv[i] = v;
        return;
    }
    const float* src; unsigned short* dst; int K, N, tile;
    if (bid < 256)       { src = wq; dst = wqkvT;          K = 512;  N = 512;  tile = bid; }
    else if (bid < 512)  { src = wk; dst = wqkvT + 262144; K = 512;  N = 512;  tile = bid - 256; }
    else if (bid < 768)  { src = wv; dst = wqkvT + 524288; K = 512;  N = 512;  tile = bid - 512; }
    else if (bid < 1024) { src = wo; dst = woT;            K = 512;  N = 512;  tile = bid - 768; }
    else if (bid < 2048) { src = w1; dst = w1T;            K = 512;  N = 2048; tile = bid - 1024; }
    else                 { src = w2; dst = w2T;            K = 2048; N = 512;  tile = bid - 2048; }
    int ntx = N >> 5;
    int n0 = (tile % ntx) * 32, k0 = (tile / ntx) * 32;
    __shared__ float tilebuf[32][33];
#pragma unroll
    for (int i = 0; i < 4; ++i)
        tilebuf[ty + 8 * i][tx] = src[(size_t)(k0 + ty + 8 * i) * N + n0 + tx];
    __syncthreads();
#pragma unroll
    for (int i = 0; i < 4; ++i)
        dst[(size_t)(n0 + ty + 8 * i) * K + k0 + tx] = f2bf(tilebuf[tx][ty + 8 * i]);
}

// ---------------- LayerNorm: fp32 [R][512] -> bf16 [R][512], 1 wave per row ----------------
__global__ __launch_bounds__(256) void ln_kernel(const float* __restrict__ x,
                                                 const float* __restrict__ w,
                                                 const float* __restrict__ b,
                                                 unsigned short* __restrict__ out) {
    int wave = threadIdx.x >> 6, lane = threadIdx.x & 63;
    size_t row = (size_t)blockIdx.x * 4 + wave;
    const float* xp = x + row * 512 + lane * 8;
    float4 v0 = *reinterpret_cast<const float4*>(xp);
    float4 v1 = *reinterpret_cast<const float4*>(xp + 4);
    float s = (v0.x + v0.y) + (v0.z + v0.w) + (v1.x + v1.y) + (v1.z + v1.w);
    float qq = v0.x * v0.x + v0.y * v0.y + v0.z * v0.z + v0.w * v0.w
             + v1.x * v1.x + v1.y * v1.y + v1.z * v1.z + v1.w * v1.w;
#pragma unroll
    for (int off = 1; off < 64; off <<= 1) {
        s += __shfl_xor(s, off, 64);
        qq += __shfl_xor(qq, off, 64);
    }
    float mu = s * (1.0f / 512.0f);
    float var = qq * (1.0f / 512.0f) - mu * mu;
    float rstd = rsqrtf(var + 1e-5f);
    int c = lane * 8;
    float4 w0 = *reinterpret_cast<const float4*>(w + c);
    float4 w1 = *reinterpret_cast<const float4*>(w + c + 4);
    float4 b0 = *reinterpret_cast<const float4*>(b + c);
    float4 b1 = *reinterpret_cast<const float4*>(b + c + 4);
    us8 r;
    r[0] = f2bf((v0.x - mu) * rstd * w0.x + b0.x);
    r[1] = f2bf((v0.y - mu) * rstd * w0.y + b0.y);
    r[2] = f2bf((v0.z - mu) * rstd * w0.z + b0.z);
    r[3] = f2bf((v0.w - mu) * rstd * w0.w + b0.w);
    r[4] = f2bf((v1.x - mu) * rstd * w1.x + b1.x);
    r[5] = f2bf((v1.y - mu) * rstd * w1.y + b1.y);
    r[6] = f2bf((v1.z - mu) * rstd * w1.z + b1.z);
    r[7] = f2bf((v1.w - mu) * rstd * w1.w + b1.w);
    *reinterpret_cast<us8*>(out + row * 512 + c) = r;
}

// ---------------- GEMM core 128x128, BK=32, double-buffered, 1 barrier/kstep ----------------
// swizzle: chunk (8 bf16) slot = c ^ (row & 3); folded into glds source address (free).
__device__ __forceinline__ void gemm_core(const unsigned short* __restrict__ A,
                                          const unsigned short* __restrict__ BT,
                                          int K, int ksteps,
                                          int m0, int n0, f32x4 (&acc)[4][4]) {
    __shared__ unsigned short As[2][4096];
    __shared__ unsigned short Bs[2][4096];
    const int tid = threadIdx.x;
    const int lane = tid & 63, wave = tid >> 6;
    const int quad = lane >> 4, l16 = lane & 15;
    const int wm = (wave >> 1) * 64, wn = (wave & 1) * 64;
    const int c0 = tid, c1 = tid + 256;
    const unsigned short* ag0 = A + (size_t)(m0 + (c0 >> 2)) * K + ((c0 & 3) ^ ((c0 >> 2) & 3)) * 8;
    const unsigned short* ag1 = A + (size_t)(m0 + (c1 >> 2)) * K + ((c1 & 3) ^ ((c1 >> 2) & 3)) * 8;
    const unsigned short* bg0 = BT + (size_t)(n0 + (c0 >> 2)) * K + ((c0 & 3) ^ ((c0 >> 2) & 3)) * 8;
    const unsigned short* bg1 = BT + (size_t)(n0 + (c1 >> 2)) * K + ((c1 & 3) ^ ((c1 >> 2) & 3)) * 8;
    const int l0 = c0 * 8, l1 = c1 * 8;
    const int sw = (quad ^ (l16 & 3)) * 8;

    // prologue: stage kstep 0 into buf 0
    gload_lds16(ag0, &As[0][0] + l0);
    gload_lds16(ag1, &As[0][0] + l1);
    gload_lds16(bg0, &Bs[0][0] + l0);
    gload_lds16(bg1, &Bs[0][0] + l1);

    for (int ks = 0; ks < ksteps; ++ks) {
        const int buf = ks & 1;
        __syncthreads();  // drains glds(ks) — issued a full kstep ago
        if (ks + 1 < ksteps) {
            const int ko = (ks + 1) * 32;
            gload_lds16(ag0 + ko, &As[buf ^ 1][0] + l0);
            gload_lds16(ag1 + ko, &As[buf ^ 1][0] + l1);
            gload_lds16(bg0 + ko, &Bs[buf ^ 1][0] + l0);
            gload_lds16(bg1 + ko, &Bs[buf ^ 1][0] + l1);
        }
        bf16x8 af[4], bf[4];
#pragma unroll
        for (int i = 0; i < 4; ++i)
            af[i] = load_frag(&As[buf][(wm + i * 16 + l16) * 32] + sw);
#pragma unroll
        for (int j = 0; j < 4; ++j)
            bf[j] = load_frag(&Bs[buf][(wn + j * 16 + l16) * 32] + sw);
#pragma unroll
        for (int i = 0; i < 4; ++i)
#pragma unroll
            for (int j = 0; j < 4; ++j)
                acc[i][j] = __builtin_amdgcn_mfma_f32_16x16x32_bf16(af[i], bf[j], acc[i][j], 0, 0, 0);
    }
}

// ---------------- GEMM core 128(M)x64(N), BK=32, double-buffered ----------------
__device__ __forceinline__ void gemm_core_n64(const unsigned short* __restrict__ A,
                                              const unsigned short* __restrict__ BT,
                                              int K, int ksteps,
                                              int m0, int n0, f32x4 (&acc)[2][4]) {
    __shared__ unsigned short As[2][4096];
    __shared__ unsigned short Bs[2][2048];
    const int tid = threadIdx.x;
    const int lane = tid & 63, wave = tid >> 6;
    const int quad = lane >> 4, l16 = lane & 15;
    const int wm = wave * 32;
    const int c0 = tid, c1 = tid + 256;
    const unsigned short* ag0 = A + (size_t)(m0 + (c0 >> 2)) * K + ((c0 & 3) ^ ((c0 >> 2) & 3)) * 8;
    const unsigned short* ag1 = A + (size_t)(m0 + (c1 >> 2)) * K + ((c1 & 3) ^ ((c1 >> 2) & 3)) * 8;
    const unsigned short* bg0 = BT + (size_t)(n0 + (c0 >> 2)) * K + ((c0 & 3) ^ ((c0 >> 2) & 3)) * 8;
    const int l0 = c0 * 8, l1 = c1 * 8;
    const int sw = (quad ^ (l16 & 3)) * 8;

    gload_lds16(ag0, &As[0][0] + l0);
    gload_lds16(ag1, &As[0][0] + l1);
    gload_lds16(bg0, &Bs[0][0] + l0);

    for (int ks = 0; ks < ksteps; ++ks) {
        const int buf = ks & 1;
        __syncthreads();
        if (ks + 1 < ksteps) {
            const int ko = (ks + 1) * 32;
            gload_lds16(ag0 + ko, &As[buf ^ 1][0] + l0);
            gload_lds16(ag1 + ko, &As[buf ^ 1][0] + l1);
            gload_lds16(bg0 + ko, &Bs[buf ^ 1][0] + l0);
        }
        bf16x8 af[2], bf[4];
#pragma unroll
        for (int i = 0; i < 2; ++i)
            af[i] = load_frag(&As[buf][(wm + i * 16 + l16) * 32] + sw);
#pragma unroll
        for (int j = 0; j < 4; ++j)
            bf[j] = load_frag(&Bs[buf][(j * 16 + l16) * 32] + sw);
#pragma unroll
        for (int i = 0; i < 2; ++i)
#pragma unroll
            for (int j = 0; j < 4; ++j)
                acc[i][j] = __builtin_amdgcn_mfma_f32_16x16x32_bf16(af[i], bf[j], acc[i][j], 0, 0, 0);
    }
}

// O-proj GEMM: out = x + A@woT + bo
__global__ __launch_bounds__(256) void gemm_oproj(const unsigned short* __restrict__ A,
                                                  const unsigned short* __restrict__ BT,
                                                  const float* __restrict__ bias,
                                                  const float* __restrict__ res,
                                                  float* __restrict__ C) {
    f32x4 acc[2][4] = {};
    const int m0 = blockIdx.y * 128, n0 = blockIdx.x * 64;
    gemm_core_n64(A, BT, 512, 16, m0, n0, acc);
    const int tid = threadIdx.x, lane = tid & 63, wave = tid >> 6;
    const int quad = lane >> 4, l16 = lane & 15;
    const int wm = wave * 32;
#pragma unroll
    for (int i = 0; i < 2; ++i)
#pragma unroll
        for (int j = 0; j < 4; ++j) {
            int n = n0 + j * 16 + l16;
            float bn = bias[n];
#pragma unroll
            for (int r = 0; r < 4; ++r) {
                int m = m0 + wm + i * 16 + quad * 4 + r;
                size_t idx = (size_t)m * 512 + n;
                C[idx] = acc[i][j][r] + bn + res[idx];
            }
        }
}

// FF2 GEMM: out += A@w2T + b2   (K=2048)
__global__ __launch_bounds__(256) void gemm_ff2(const unsigned short* __restrict__ A,
                                                const unsigned short* __restrict__ BT,
                                                const float* __restrict__ bias,
                                                float* __restrict__ C) {
    f32x4 acc[2][4] = {};
    const int m0 = blockIdx.y * 128, n0 = blockIdx.x * 64;
    gemm_core_n64(A, BT, 2048, 64, m0, n0, acc);
    const int tid = threadIdx.x, lane = tid & 63, wave = tid >> 6;
    const int quad = lane >> 4, l16 = lane & 15;
    const int wm = wave * 32;
#pragma unroll
    for (int i = 0; i < 2; ++i)
#pragma unroll
        for (int j = 0; j < 4; ++j) {
            int n = n0 + j * 16 + l16;
            float bn = bias[n];
#pragma unroll
            for (int r = 0; r < 4; ++r) {
                int m = m0 + wm + i * 16 + quad * 4 + r;
                size_t idx = (size_t)m * 512 + n;
                C[idx] = C[idx] + acc[i][j][r] + bn;
            }
        }
}

// QKV GEMM: writes Q,K into qk[token][1024] (bf16) and V transposed into vT[b*512+hd][2048]
__global__ __launch_bounds__(256) void gemm_qkv_k(const unsigned short* __restrict__ A,
                                                  const unsigned short* __restrict__ BT,
                                                  const float* __restrict__ bias,
                                                  unsigned short* __restrict__ qk,
                                                  unsigned short* __restrict__ vT) {
    f32x4 acc[4][4] = {};
    const int m0 = blockIdx.y * 128, n0 = blockIdx.x * 128;
    gemm_core(A, BT, 512, 16, m0, n0, acc);
    const int tid = threadIdx.x, lane = tid & 63, wave = tid >> 6;
    const int quad = lane >> 4, l16 = lane & 15;
    const int wm = (wave >> 1) * 64, wn = (wave & 1) * 64;
    if (n0 < 1024) {
#pragma unroll
        for (int i = 0; i < 4; ++i)
#pragma unroll
            for (int j = 0; j < 4; ++j) {
                int n = n0 + wn + j * 16 + l16;
                float bn = bias[n];
#pragma unroll
                for (int r = 0; r < 4; ++r) {
                    int m = m0 + wm + i * 16 + quad * 4 + r;
                    qk[(size_t)m * 1024 + n] = f2bf(acc[i][j][r] + bn);
                }
            }
    } else {
#pragma unroll
        for (int i = 0; i < 4; ++i) {
            int mb = m0 + wm + i * 16 + quad * 4;
            int bb = mb >> 11, tok = mb & 2047;
#pragma unroll
            for (int j = 0; j < 4; ++j) {
                int n = n0 + wn + j * 16 + l16;
                float bn = bias[n];
                int hd = n - 1024;
                ushort4 pk;
                pk.x = f2bf(acc[i][j][0] + bn);
                pk.y = f2bf(acc[i][j][1] + bn);
                pk.z = f2bf(acc[i][j][2] + bn);
                pk.w = f2bf(acc[i][j][3] + bn);
                *reinterpret_cast<ushort4*>(vT + (size_t)(bb * 512 + hd) * 2048 + tok) = pk;
            }
        }
    }
}

// FF1 GEMM: GELU epilogue, bf16 store
__global__ __launch_bounds__(256) void gemm_gelu_k(const unsigned short* __restrict__ A,
                                                   const unsigned short* __restrict__ BT,
                                                   const float* __restrict__ bias,
                                                   unsigned short* __restrict__ C) {
    f32x4 acc[4][4] = {};
    const int m0 = blockIdx.y * 128, n0 = blockIdx.x * 128;
    gemm_core(A, BT, 512, 16, m0, n0, acc);
    const int tid = threadIdx.x, lane = tid & 63, wave = tid >> 6;
    const int quad = lane >> 4, l16 = lane & 15;
    const int wm = (wave >> 1) * 64, wn = (wave & 1) * 64;
#pragma unroll
    for (int i = 0; i < 4; ++i)
#pragma unroll
        for (int j = 0; j < 4; ++j) {
            int n = n0 + wn + j * 16 + l16;
            float bn = bias[n];
#pragma unroll
            for (int r = 0; r < 4; ++r) {
                int m = m0 + wm + i * 16 + quad * 4 + r;
                float val = acc[i][j][r] + bn;
                float g = 0.5f * val * (1.0f + erff(val * 0.70710678118654752f));
                C[(size_t)m * 2048 + n] = f2bf(g);
            }
        }
}

// ---------------- flash attention: 2 batches per block, shared bias tile ----------------
// grid (32 qb, 8 h, 2 bp); double-buffered glds K/V^T; fixed-shift softmax; swizzled LDS.
// Barrier B is lgkm-only: next-tile glds stays in flight until barrier A (full-tile cover).
__global__ __launch_bounds__(256) void attn_kernel(const unsigned short* __restrict__ qk,
                                                   const unsigned short* __restrict__ vT,
                                                   const float* __restrict__ bias,
                                                   unsigned short* __restrict__ o) {
    __shared__ unsigned short Ks[2][2][4096];   // [buf][batch][krow][d] chunk swizzle cl^(row&7)
    __shared__ unsigned short VTs[2][2][4096];  // [buf][batch][d][kt]
    __shared__ unsigned short Ps[2][4096];      // [batch][wave][m][kt]
    const int tid = threadIdx.x;
    const int lane = tid & 63, wave = tid >> 6, quad = lane >> 4, l16 = lane & 15;
    const int qb = blockIdx.x, h = blockIdx.y, bp = blockIdx.z;
    const int qw = qb * 64 + wave * 16;

    bf16x8 qf[2][2];
#pragma unroll
    for (int bi = 0; bi < 2; ++bi) {
        const unsigned short* qbase =
            qk + (size_t)((bp * 2 + bi) * 2048 + qw + l16) * 1024 + h * 64 + quad * 8;
        qf[bi][0] = load_frag(qbase);
        qf[bi][1] = load_frag(qbase + 32);
    }

    f32x4 Oacc[2][4] = {};
    float lsum[2][4] = {};

    const int p8 = lane & 7;
    const int r0 = wave * 16 + (lane >> 3);
    const int swz = (p8 ^ (r0 & 7)) * 8;
    const unsigned short* kg[2];
    const unsigned short* vg[2];
#pragma unroll
    for (int bi = 0; bi < 2; ++bi) {
        int b = bp * 2 + bi;
        kg[bi] = qk + (size_t)(b * 2048 + r0) * 1024 + 512 + h * 64 + swz;
        vg[bi] = vT + (size_t)(b * 512 + h * 64 + r0) * 2048 + swz;
    }
    const int ldst = r0 * 64 + p8 * 8;

    const float* brow = bias + (size_t)h * 2048 * 2048 + (size_t)(qw + quad * 4) * 2048 + l16;
    const float S2 = 0.18033688011112042f;   // 0.125 * log2(e)
    const float K2 = 1.4426950408889634f;    // log2(e)
    const float C2 = -11.541560327111707f;   // -8 * log2(e)

    // prefetch tile 0
#pragma unroll
    for (int bi = 0; bi < 2; ++bi) {
        gload_lds16(kg[bi], &Ks[0][bi][0] + ldst);
        gload_lds16(kg[bi] + 8 * 1024, &Ks[0][bi][512] + ldst);
        gload_lds16(vg[bi], &VTs[0][bi][0] + ldst);
        gload_lds16(vg[bi] + 8 * 2048, &VTs[0][bi][512] + ldst);
    }
    float bbf[4][4];
#pragma unroll
    for (int t = 0; t < 4; ++t)
#pragma unroll
        for (int r = 0; r < 4; ++r)
            bbf[t][r] = fmaf(brow[(size_t)r * 2048 + t * 16], K2, C2);

    const int sw7 = l16 & 7;
    for (int kt = 0; kt < 32; ++kt) {
        const int buf = kt & 1;
        __syncthreads();  // barrier A: drains glds(kt) (full-tile cover); prev tile consumed
        if (kt < 31) {
#pragma unroll
            for (int bi = 0; bi < 2; ++bi) {
                const unsigned short* kg2 = kg[bi] + (size_t)(kt + 1) * 64 * 1024;
                const unsigned short* vg2 = vg[bi] + (kt + 1) * 64;
                gload_lds16(kg2, &Ks[buf ^ 1][bi][0] + ldst);
                gload_lds16(kg2 + 8 * 1024, &Ks[buf ^ 1][bi][512] + ldst);
                gload_lds16(vg2, &VTs[buf ^ 1][bi][0] + ldst);
                gload_lds16(vg2 + 8 * 2048, &VTs[buf ^ 1][bi][512] + ldst);
            }
        }
        // S = Q K^T -> exp -> P (both batches, shared bbf)
#pragma unroll
        for (int bi = 0; bi < 2; ++bi) {
#pragma unroll
            for (int t = 0; t < 4; ++t) {
                const unsigned short* krow = &Ks[buf][bi][(t * 16 + l16) * 64];
                bf16x8 kb0 = load_frag(krow + ((quad ^ sw7) * 8));
                bf16x8 kb1 = load_frag(krow + (((quad + 4) ^ sw7) * 8));
                f32x4 c = {};
                c = __builtin_amdgcn_mfma_f32_16x16x32_bf16(qf[bi][0], kb0, c, 0, 0, 0);
                c = __builtin_amdgcn_mfma_f32_16x16x32_bf16(qf[bi][1], kb1, c, 0, 0, 0);
#pragma unroll
                for (int r = 0; r < 4; ++r) {
                    float e = __builtin_amdgcn_exp2f(fmaf(c[r], S2, bbf[t][r]));
                    lsum[bi][r] += e;
                    int m = quad * 4 + r;
                    int phys = (t * 2 + (l16 >> 3)) ^ ((m >> 1) & 7);
                    Ps[bi][wave * 1024 + m * 64 + phys * 8 + (l16 & 7)] = f2bf(e);
                }
            }
        }
        barrier_lds_only();  // barrier B: P visible; glds(kt+1) stays in flight
        // prefetch next tile's bias (shared by both batches; overlaps PV)
        if (kt < 31) {
            const float* b2 = brow + (size_t)(kt + 1) * 64;
#pragma unroll
            for (int t = 0; t < 4; ++t)
#pragma unroll
                for (int r = 0; r < 4; ++r)
                    bbf[t][r] = fmaf(b2[(size_t)r * 2048 + t * 16], K2, C2);
        }
        // O += P V (both batches)
#pragma unroll
        for (int bi = 0; bi < 2; ++bi) {
            const unsigned short* prow = &Ps[bi][wave * 1024 + l16 * 64];
            bf16x8 pa0 = load_frag(prow + ((quad ^ ((l16 >> 1) & 7)) * 8));
            bf16x8 pa1 = load_frag(prow + (((quad + 4) ^ ((l16 >> 1) & 7)) * 8));
#pragma unroll
            for (int t = 0; t < 4; ++t) {
                const unsigned short* vrow = &VTs[buf][bi][(t * 16 + l16) * 64];
                bf16x8 vb0 = load_frag(vrow + ((quad ^ sw7) * 8));
                bf16x8 vb1 = load_frag(vrow + (((quad + 4) ^ sw7) * 8));
                Oacc[bi][t] = __builtin_amdgcn_mfma_f32_16x16x32_bf16(pa0, vb0, Oacc[bi][t], 0, 0, 0);
                Oacc[bi][t] = __builtin_amdgcn_mfma_f32_16x16x32_bf16(pa1, vb1, Oacc[bi][t], 0, 0, 0);
            }
        }
    }

    // reduce row sums over 16 k-lanes, store O / l
#pragma unroll
    for (int off = 1; off < 16; off <<= 1)
#pragma unroll
        for (int bi = 0; bi < 2; ++bi)
#pragma unroll
            for (int r = 0; r < 4; ++r) lsum[bi][r] += __shfl_xor(lsum[bi][r], off, 64);
#pragma unroll
    for (int bi = 0; bi < 2; ++bi)
#pragma unroll
        for (int r = 0; r < 4; ++r) {
            float inv = 1.0f / lsum[bi][r];
            int qg = qw + quad * 4 + r;
            unsigned short* op = o + (size_t)((bp * 2 + bi) * 2048 + qg) * 512 + h * 64;
#pragma unroll
            for (int t = 0; t < 4; ++t) op[t * 16 + l16] = f2bf(Oacc[bi][t][r] * inv);
        }
}

extern "C" void kernel_launch(void* const* d_in, const int* in_sizes, int n_in,
                              void* d_out, int out_size, void* d_ws, size_t ws_size,
                              hipStream_t stream) {
    const float* x      = (const float*)d_in[0];
    const float* abias  = (const float*)d_in[1];
    const float* ln1_w  = (const float*)d_in[2];
    const float* ln1_b  = (const float*)d_in[3];
    const float* ln2_w  = (const float*)d_in[4];
    const float* ln2_b  = (const float*)d_in[5];
    const float* wq     = (const float*)d_in[6];
    const float* bq     = (const float*)d_in[7];
    const float* wk     = (const float*)d_in[8];
    const float* bk     = (const float*)d_in[9];
    const float* wv     = (const float*)d_in[10];
    const float* bv     = (const float*)d_in[11];
    const float* wo     = (const float*)d_in[12];
    const float* bo     = (const float*)d_in[13];
    const float* w1     = (const float*)d_in[14];
    const float* b1     = (const float*)d_in[15];
    const float* w2     = (const float*)d_in[16];
    const float* b2     = (const float*)d_in[17];
    float* out = (float*)d_out;

    char* ws = (char*)d_ws;
    unsigned short* wqkvT  = (unsigned short*)(ws + 0);          // [1536][512] bf16
    unsigned short* woT    = (unsigned short*)(ws + 1572864);    // [512][512]
    unsigned short* w1T    = (unsigned short*)(ws + 2097152);    // [2048][512]
    unsigned short* w2T    = (unsigned short*)(ws + 4194304);    // [512][2048]
    float*          biasqkv= (float*)(ws + 6291456);             // [1536]
    unsigned short* hbuf   = (unsigned short*)(ws + 6297600);    // [8192][512] bf16 (h / h2)
    unsigned short* qkbuf  = (unsigned short*)(ws + 14686208);   // [8192][1024] bf16 (Q|K)
    unsigned short* vTbuf  = (unsigned short*)(ws + 31463424);   // [4*512][2048] bf16 (V^T per b,h)
    unsigned short* o_attn = (unsigned short*)(ws + 39852032);   // [8192][512] bf16
    unsigned short* ff1    = (unsigned short*)(ws + 48240640);   // [8192][2048] bf16

    // weights transpose/cast + bias concat
    prep_kernel<<<3078, dim3(32, 8), 0, stream>>>(wq, wk, wv, wo, w1, w2, bq, bk, bv,
                                                  wqkvT, woT, w1T, w2T, biasqkv);
    // h = LN1(x)
    ln_kernel<<<2048, 256, 0, stream>>>(x, ln1_w, ln1_b, hbuf);
    // qkbuf/vT = h @ [wq|wk|wv] + biases  (V written transposed)
    gemm_qkv_k<<<dim3(12, 64), 256, 0, stream>>>(hbuf, wqkvT, biasqkv, qkbuf, vTbuf);
    // o_attn = attention(q,k,v, bias) — 2 batches per block share the bias tile
    attn_kernel<<<dim3(32, 8, 2), 256, 0, stream>>>(qkbuf, vTbuf, abias, o_attn);
    // out = x + o_attn @ wo + bo
    gemm_oproj<<<dim3(8, 64), 256, 0, stream>>>(o_attn, woT, bo, x, out);
    // h2 = LN2(out)
    ln_kernel<<<2048, 256, 0, stream>>>(out, ln2_w, ln2_b, hbuf);
    // ff1 = GELU(h2 @ w1 + b1)
    gemm_gelu_k<<<dim3(16, 64), 256, 0, stream>>>(hbuf, w1T, b1, ff1);
    // out += ff1 @ w2 + b2
    gemm_ff2<<<dim3(8, 64), 256, 0, stream>>>(ff1, w2T, b2, out);
}